// Round 5
// baseline (41782.620 us; speedup 1.0000x reference)
//
#include <hip/hip_runtime.h>
#include <math.h>

#define HID 512
#define FEAT 128
#define SEQL 512
#define PREDL 128
#define NWG 256
#define HK 516   // LDS row stride (floats) for h tiles
#define EK 132   // LDS row stride for x/e tiles

typedef float v2f __attribute__((ext_vector_type(2)));

__device__ __forceinline__ float sigf_(float x) { return 1.0f / (1.0f + __expf(-x)); }
__device__ __forceinline__ float tanh_(float x) {
  float ax = fabsf(x);
  float e2 = __expf(-2.0f * ax);
  return copysignf((1.0f - e2) / (1.0f + e2), x);
}
__device__ __forceinline__ v2f mkv2(float a, float b) { v2f r; r[0] = a; r[1] = b; return r; }

__device__ __forceinline__ void stg_sc(float* p, float v) {
  __hip_atomic_store(p, v, __ATOMIC_RELAXED, __HIP_MEMORY_SCOPE_AGENT);
}

// bt-local barrier (32 WGs/group), relaxed agent atomics only (rounds 3/4 verified)
__device__ __forceinline__ void bar_arrive(int* __restrict__ bar, int grp,
                                           int phase, int tid, bool& last) {
  __syncthreads();
  if (tid == 0) {
    const int a = __hip_atomic_fetch_add(bar + grp * 32, 1, __ATOMIC_RELAXED,
                                         __HIP_MEMORY_SCOPE_AGENT);
    last = (a == 32 * phase - 1);
    if (last)
      __hip_atomic_store(bar + 512 + grp * 32, phase, __ATOMIC_RELAXED,
                         __HIP_MEMORY_SCOPE_AGENT);
  }
  asm volatile("" ::: "memory");
}
__device__ __forceinline__ void bar_wait(int* __restrict__ bar, int grp,
                                         int phase, int tid, bool last) {
  asm volatile("" ::: "memory");
  if (tid == 0 && !last) {
    while (__hip_atomic_load(bar + 512 + grp * 32, __ATOMIC_RELAXED,
                             __HIP_MEMORY_SCOPE_AGENT) < phase)
      __builtin_amdgcn_s_sleep(1);
  }
  __syncthreads();
}

// stage one 16b x 512k tile (coherent sc0 sc1 loads), 512 lanes x 4 loads
__device__ __forceinline__ void stage4(float* __restrict__ dst,
                                       const float* __restrict__ src,
                                       int b0, int lane512) {
  const int kb = lane512 >> 2;
  const int bq = (lane512 & 3) * 4;
  const float* p0 = src + (size_t)kb * 128 + b0 + bq;
  const float* p1 = src + ((size_t)kb + 128) * 128 + b0 + bq;
  const float* p2 = src + ((size_t)kb + 256) * 128 + b0 + bq;
  const float* p3 = src + ((size_t)kb + 384) * 128 + b0 + bq;
  float4 r0, r1, r2, r3;
  asm volatile(
      "global_load_dwordx4 %0, %4, off sc0 sc1\n\t"
      "global_load_dwordx4 %1, %5, off sc0 sc1\n\t"
      "global_load_dwordx4 %2, %6, off sc0 sc1\n\t"
      "global_load_dwordx4 %3, %7, off sc0 sc1\n\t"
      "s_waitcnt vmcnt(0)"
      : "=&v"(r0), "=&v"(r1), "=&v"(r2), "=&v"(r3)
      : "v"(p0), "v"(p1), "v"(p2), "v"(p3)
      : "memory");
  dst[(bq + 0) * HK + kb] = r0.x; dst[(bq + 1) * HK + kb] = r0.y;
  dst[(bq + 2) * HK + kb] = r0.z; dst[(bq + 3) * HK + kb] = r0.w;
  dst[(bq + 0) * HK + kb + 128] = r1.x; dst[(bq + 1) * HK + kb + 128] = r1.y;
  dst[(bq + 2) * HK + kb + 128] = r1.z; dst[(bq + 3) * HK + kb + 128] = r1.w;
  dst[(bq + 0) * HK + kb + 256] = r2.x; dst[(bq + 1) * HK + kb + 256] = r2.y;
  dst[(bq + 2) * HK + kb + 256] = r2.z; dst[(bq + 3) * HK + kb + 256] = r2.w;
  dst[(bq + 0) * HK + kb + 384] = r3.x; dst[(bq + 1) * HK + kb + 384] = r3.y;
  dst[(bq + 2) * HK + kb + 384] = r3.z; dst[(bq + 3) * HK + kb + 384] = r3.w;
}
// x tile: 512 lanes x 1 float4 (plain cached loads, read-only input)
__device__ __forceinline__ void stage_x1(float* __restrict__ dst,
                                         const float* __restrict__ x, int t,
                                         int b0, int lane512) {
  const int bb = lane512 >> 5;
  const int fq = (lane512 & 31) * 4;
  const float4 v =
      *(const float4*)(x + ((size_t)(b0 + bb) * SEQL + t) * FEAT + fq);
  *(float4*)(dst + bb * EK + fq) = v;
}

// ---- packed-FMA GEMV primitives ------------------------------------------
__device__ __forceinline__ void pkf(v2f& a01, v2f& a23, float4 w, float h) {
  v2f hh; hh[0] = h; hh[1] = h;
  v2f lo; lo[0] = w.x; lo[1] = w.y;
  v2f hi; hi[0] = w.z; hi[1] = w.w;
  a01 = __builtin_elementwise_fma(lo, hh, a01);
  a23 = __builtin_elementwise_fma(hi, hh, a23);
}
// dual-matrix fused stream over [k4b,k4e)
__device__ __forceinline__ void gemv_fused8(v2f& a01, v2f& a23,
                                            const float4* __restrict__ W8,
                                            size_t base,
                                            const float* __restrict__ rA,
                                            const float* __restrict__ rB,
                                            int k4b, int k4e) {
#pragma unroll 2
  for (int k4 = k4b; k4 < k4e; ++k4) {
    const float4 hA = *(const float4*)(rA + k4 * 4);
    const float4 hB = *(const float4*)(rB + k4 * 4);
    const size_t o = base + (size_t)k4 * 8;
    pkf(a01, a23, W8[o + 0], hA.x); pkf(a01, a23, W8[o + 1], hB.x);
    pkf(a01, a23, W8[o + 2], hA.y); pkf(a01, a23, W8[o + 3], hB.y);
    pkf(a01, a23, W8[o + 4], hA.z); pkf(a01, a23, W8[o + 5], hB.z);
    pkf(a01, a23, W8[o + 6], hA.w); pkf(a01, a23, W8[o + 7], hB.w);
  }
}
// one half of a dual stream over [k4b,k4e)
__device__ __forceinline__ void gemv_half8(v2f& a01, v2f& a23,
                                           const float4* __restrict__ W8,
                                           size_t base, int sel,
                                           const float* __restrict__ row,
                                           int k4b, int k4e) {
#pragma unroll 4
  for (int k4 = k4b; k4 < k4e; ++k4) {
    const float4 h = *(const float4*)(row + k4 * 4);
    const size_t o = base + (size_t)k4 * 8 + sel;
    pkf(a01, a23, W8[o + 0], h.x);
    pkf(a01, a23, W8[o + 2], h.y);
    pkf(a01, a23, W8[o + 4], h.z);
    pkf(a01, a23, W8[o + 6], h.w);
  }
}
// plain 4-interleaved stream over [k4b,k4e)
__device__ __forceinline__ void gemv_p4(v2f& a01, v2f& a23,
                                        const float4* __restrict__ W4,
                                        size_t base,
                                        const float* __restrict__ row,
                                        int k4b, int k4e) {
#pragma unroll 4
  for (int k4 = k4b; k4 < k4e; ++k4) {
    const float4 h = *(const float4*)(row + k4 * 4);
    const size_t o = base + (size_t)k4 * 4;
    pkf(a01, a23, W4[o + 0], h.x);
    pkf(a01, a23, W4[o + 1], h.y);
    pkf(a01, a23, W4[o + 2], h.z);
    pkf(a01, a23, W4[o + 3], h.w);
  }
}

__device__ __forceinline__ void act_store(v2f a01, v2f a23, float& c_reg,
                                          float* __restrict__ HoutT,
                                          size_t cit) {
  const float ig = sigf_(a01[0]), fg = sigf_(a01[1]);
  const float gg = tanh_(a23[0]), og = sigf_(a23[1]);
  const float cn = fg * c_reg + ig * gg;
  c_reg = cn;
  stg_sc(HoutT + cit, og * tanh_(cn));
}

// ---------------------------------------------------------------------------
// Persistent kernel: 256 WGs x 1024 threads (16 waves/CU), ~93KB LDS.
// crew A (tid<512): LSTM0, 2-way k-split. crew B: LSTM1 / decode.
// ---------------------------------------------------------------------------
__global__ __launch_bounds__(1024, 1) void k_persist(
    const float* __restrict__ x,
    const float* __restrict__ enc2, const float* __restrict__ enc_b,
    const float* __restrict__ wih04, const float* __restrict__ Wa8,
    const float* __restrict__ Wf8,
    const float* __restrict__ bih0, const float* __restrict__ bhh0,
    const float* __restrict__ bih1, const float* __restrict__ bhh1,
    const float* __restrict__ dec4, const float* __restrict__ dec_b,
    const float* __restrict__ bcomp,
    float* __restrict__ h0A, float* __restrict__ h0B,
    float* __restrict__ h1A, float* __restrict__ h1B,
    int* __restrict__ bar, float* __restrict__ out) {
  __shared__ float s_h0[16 * HK];
  __shared__ float s_h1[16 * HK];
  __shared__ float s_x[16 * EK];
  __shared__ float s_e[16 * EK];
  __shared__ float4 s_red4[768];

  const int wg = blockIdx.x;
  const int tid = threadIdx.x;
  const int ut = (wg & 7) * 4 + ((wg >> 3) & 3);  // XCD-affine unit tile
  const int bt = wg >> 5;
  const int b0 = bt * 16;
  const int o = tid & 255;
  const int u = o >> 4, b = o & 15;
  const int ug = ut * 16 + u;
  const size_t cit = (size_t)ug * 128 + b0 + b;
  const int crewB = tid >> 9;
  const int khalf = (tid >> 8) & 1;
  const int lane512 = tid & 511;
  const int q4 = ((tid >> 8) + 2) & 3;  // 4-way split id (owners q4==0)

  float* h0b[2] = {h0A, h0B};
  float* h1b[2] = {h1A, h1B};
  const float* sh0row = s_h0 + b * HK;
  const float* sh1row = s_h1 + b * HK;
  const float* serow = s_e + b * EK;

  const float4* W8a = (const float4*)Wa8;   // [Wcomp | whh0]
  const float4* W8f = (const float4*)Wf8;   // [wih1 | whh1]
  const float4* W4i = (const float4*)wih04;
  const size_t baseG = (size_t)ug * 1024;
  const size_t baseI = (size_t)ug * 128;

  const float bt00 = bih0[ug] + bhh0[ug];
  const float bt01 = bih0[512 + ug] + bhh0[512 + ug];
  const float bt02 = bih0[1024 + ug] + bhh0[1024 + ug];
  const float bt03 = bih0[1536 + ug] + bhh0[1536 + ug];
  const float ba00 = bt00 + bcomp[ug];
  const float ba01 = bt01 + bcomp[512 + ug];
  const float ba02 = bt02 + bcomp[1024 + ug];
  const float ba03 = bt03 + bcomp[1536 + ug];
  const float b10 = bih1[ug] + bhh1[ug];
  const float b11 = bih1[512 + ug] + bhh1[512 + ug];
  const float b12 = bih1[1024 + ug] + bhh1[1024 + ug];
  const float b13 = bih1[1536 + ug] + bhh1[1536 + ug];

  // encoder role (all 1024 threads): 2 f-outputs for one batch
  const int eb = tid & 15;
  const int f2 = tid >> 4;                         // 0..63
  const float4* EF4 = (const float4*)enc2 + (size_t)f2 * 64;
  const float encb0 = enc_b[f2 * 2], encb1 = enc_b[f2 * 2 + 1];
  const float* sxrow = s_x + eb * EK;

  // decoder role (crew B in AR): 4 dec rows x 1 batch per thread
  const int cb = tid & 511;
  const int jq = cb >> 4, db = cb & 15;
  const float4* D4 = (const float4*)dec4;
  const size_t baseD = (size_t)jq * 512;
  const float db0 = dec_b[jq * 4], db1 = dec_b[jq * 4 + 1];
  const float db2 = dec_b[jq * 4 + 2], db3 = dec_b[jq * 4 + 3];
  const float* dhrow = s_h1 + db * HK;

  float c_reg = 0.0f;  // c0 for crew A owners, c1 for crew B owners
  int ph = 0;
  bool lastf = false;

  // ================= teacher-forced phase ==================================
  if (tid < 512) stage_x1(s_x, x, 0, b0, lane512);
  for (int t = 0; t < SEQL; ++t) {
    const float* h0in = h0b[(t + 1) & 1];
    float* h0out = h0b[t & 1];
    const float* h1in = h1b[t & 1];
    float* h1out = h1b[(t + 1) & 1];

    if (tid < 512) stage4(s_h0, h0in, b0, lane512);
    else stage4(s_h1, h1in, b0, lane512);
    __syncthreads();

    {  // cooperative encoder: 2 outputs per thread
      v2f acc = mkv2(encb0, encb1);
#pragma unroll 8
      for (int k2 = 0; k2 < 64; ++k2) {
        const float4 w = EF4[k2];
        const float hv0 = sxrow[2 * k2], hv1 = sxrow[2 * k2 + 1];
        acc = __builtin_elementwise_fma(mkv2(w.x, w.y), mkv2(hv0, hv0), acc);
        acc = __builtin_elementwise_fma(mkv2(w.z, w.w), mkv2(hv1, hv1), acc);
      }
      s_e[eb * EK + f2 * 2] = acc[0];
      s_e[eb * EK + f2 * 2 + 1] = acc[1];
    }
    __syncthreads();

    v2f a01, a23;
    if (!crewB) {  // LSTM0(t), 2-way k-split
      if (!khalf) {
        a01 = mkv2(bt00, bt01); a23 = mkv2(bt02, bt03);
        gemv_half8(a01, a23, W8a, baseG, 1, sh0row, 0, 80);
      } else {
        a01 = mkv2(0.f, 0.f); a23 = mkv2(0.f, 0.f);
        gemv_half8(a01, a23, W8a, baseG, 1, sh0row, 80, 128);
        gemv_p4(a01, a23, W4i, baseI, serow, 0, 32);
        s_red4[o] = make_float4(a01[0], a01[1], a23[0], a23[1]);
      }
    } else {  // LSTM1(t-1), 2-way k-split
      if (!khalf) {
        a01 = mkv2(b10, b11); a23 = mkv2(b12, b13);
        gemv_fused8(a01, a23, W8f, baseG, sh0row, sh1row, 0, 64);
      } else {
        a01 = mkv2(0.f, 0.f); a23 = mkv2(0.f, 0.f);
        gemv_fused8(a01, a23, W8f, baseG, sh0row, sh1row, 64, 128);
        s_red4[256 + o] = make_float4(a01[0], a01[1], a23[0], a23[1]);
      }
    }
    __syncthreads();
    if (!khalf) {
      const float4 p = s_red4[(crewB ? 256 : 0) + o];
      a01[0] += p.x; a01[1] += p.y; a23[0] += p.z; a23[1] += p.w;
      if (!crewB) act_store(a01, a23, c_reg, h0out, cit);
      else if (t > 0) act_store(a01, a23, c_reg, h1out, cit);
    }
    bar_arrive(bar, bt, ++ph, tid, lastf);
    if (tid < 512 && t + 1 < SEQL) stage_x1(s_x, x, t + 1, b0, lane512);
    bar_wait(bar, bt, ph, tid, lastf);
  }

  // ================= LSTM1(511), 4-way k-split =============================
  if (tid < 512) stage4(s_h0, h0b[1], b0, lane512);
  else stage4(s_h1, h1b[0], b0, lane512);
  __syncthreads();
  {
    v2f a01, a23;
    if (q4 == 0) { a01 = mkv2(b10, b11); a23 = mkv2(b12, b13); }
    else { a01 = mkv2(0.f, 0.f); a23 = mkv2(0.f, 0.f); }
    gemv_fused8(a01, a23, W8f, baseG, sh0row, sh1row, q4 * 32, q4 * 32 + 32);
    if (q4) s_red4[(q4 - 1) * 256 + o] = make_float4(a01[0], a01[1], a23[0], a23[1]);
    __syncthreads();
    if (q4 == 0) {
      const float4 p0 = s_red4[o], p1 = s_red4[256 + o], p2 = s_red4[512 + o];
      a01[0] += p0.x + p1.x + p2.x; a01[1] += p0.y + p1.y + p2.y;
      a23[0] += p0.z + p1.z + p2.z; a23[1] += p0.w + p1.w + p2.w;
      act_store(a01, a23, c_reg, h1b[1], cit);
    }
  }
  bar_arrive(bar, bt, ++ph, tid, lastf);
  bar_wait(bar, bt, ph, tid, lastf);

  // ================= autoregressive phase ==================================
  for (int t = SEQL; t < SEQL + PREDL - 1; ++t) {
    const float* h1prev = h1b[(t + 1) & 1];
    const float* h0prev = h0b[(t + 1) & 1];
    float* h0cur = h0b[t & 1];
    float* h1cur = h1b[t & 1];

    // ---- phase 1: crew A LSTM0-AR(t) 2-way; crew B decode h1(t-1) --------
    if (tid < 512) stage4(s_h1, h1prev, b0, lane512);
    else stage4(s_h0, h0prev, b0, lane512);
    __syncthreads();
    v2f a01, a23;
    if (!crewB) {
      if (!khalf) { a01 = mkv2(ba00, ba01); a23 = mkv2(ba02, ba03); }
      else { a01 = mkv2(0.f, 0.f); a23 = mkv2(0.f, 0.f); }
      gemv_fused8(a01, a23, W8a, baseG, sh1row, sh0row,
                  khalf ? 64 : 0, khalf ? 128 : 64);
      if (khalf) s_red4[o] = make_float4(a01[0], a01[1], a23[0], a23[1]);
    } else {
      v2f d01 = mkv2(db0, db1), d23 = mkv2(db2, db3);
      gemv_p4(d01, d23, D4, baseD, dhrow, 0, 128);
      *(float4*)(out + ((size_t)(b0 + db) * PREDL + (t - SEQL)) * FEAT + jq * 4) =
          make_float4(d01[0], d01[1], d23[0], d23[1]);
    }
    __syncthreads();
    if (!crewB && !khalf) {
      const float4 p = s_red4[o];
      a01[0] += p.x; a01[1] += p.y; a23[0] += p.z; a23[1] += p.w;
      act_store(a01, a23, c_reg, h0cur, cit);
    }
    bar_arrive(bar, bt, ++ph, tid, lastf);
    bar_wait(bar, bt, ph, tid, lastf);

    // ---- phase 2: LSTM1(t), 4-way k-split (all 1024 threads) -------------
    if (tid < 512) stage4(s_h0, h0cur, b0, lane512);
    __syncthreads();
    {
      v2f c01, c23;
      if (q4 == 0) { c01 = mkv2(b10, b11); c23 = mkv2(b12, b13); }
      else { c01 = mkv2(0.f, 0.f); c23 = mkv2(0.f, 0.f); }
      gemv_fused8(c01, c23, W8f, baseG, sh0row, sh1row, q4 * 32, q4 * 32 + 32);
      if (q4) s_red4[(q4 - 1) * 256 + o] = make_float4(c01[0], c01[1], c23[0], c23[1]);
      __syncthreads();
      if (q4 == 0) {
        const float4 p0 = s_red4[o], p1 = s_red4[256 + o], p2 = s_red4[512 + o];
        c01[0] += p0.x + p1.x + p2.x; c01[1] += p0.y + p1.y + p2.y;
        c23[0] += p0.z + p1.z + p2.z; c23[1] += p0.w + p1.w + p2.w;
        act_store(c01, c23, c_reg, h1cur, cit);
      }
    }
    bar_arrive(bar, bt, ++ph, tid, lastf);
    bar_wait(bar, bt, ph, tid, lastf);
  }

  // ================= final output: decode h1(638), step 127 ================
  if (tid < 512) stage4(s_h1, h1b[0], b0, lane512);
  __syncthreads();
  if (crewB) {
    v2f d01 = mkv2(db0, db1), d23 = mkv2(db2, db3);
    gemv_p4(d01, d23, D4, baseD, dhrow, 0, 128);
    *(float4*)(out + ((size_t)(b0 + db) * PREDL + (PREDL - 1)) * FEAT + jq * 4) =
        make_float4(d01[0], d01[1], d23[0], d23[1]);
  }
}

// ===== prologue ============================================================
__global__ void k_b1(const float* __restrict__ enc_w,
                     const float* __restrict__ dec_w, float* __restrict__ B1) {
  const int idx = blockIdx.x * 256 + threadIdx.x;
  const int j = idx >> 9, m = idx & 511;
  float acc = 0.0f;
  for (int k = 0; k < FEAT; ++k) acc += enc_w[j * FEAT + k] * dec_w[k * HID + m];
  B1[idx] = acc;
}
__global__ void k_te(const float* __restrict__ enc_w,
                     const float* __restrict__ enc_b,
                     const float* __restrict__ dec_b, float* __restrict__ te) {
  const int j = threadIdx.x;
  float acc = enc_b[j];
  for (int k = 0; k < FEAT; ++k) acc += dec_b[k] * enc_w[j * FEAT + k];
  te[j] = acc;
}
__global__ void k_bcomp(const float* __restrict__ wih0,
                        const float* __restrict__ te, float* __restrict__ bc) {
  const int n = blockIdx.x * 256 + threadIdx.x;
  float acc = 0.0f;
  for (int j = 0; j < FEAT; ++j) acc += wih0[n * FEAT + j] * te[j];
  bc[n] = acc;
}
// Wa8[(u*512+k)*8 + g] = Wcomp(g,u,k);  +4+g = whh0(g,u,k)
__global__ void k_wa8(const float* __restrict__ wih0,
                      const float* __restrict__ B1,
                      const float* __restrict__ whh0, float* __restrict__ W) {
  const int idx = blockIdx.x * 256 + threadIdx.x;
  const int uu = idx >> 9, k = idx & 511;
  float c[4];
#pragma unroll
  for (int g = 0; g < 4; ++g) {
    const float* wr = wih0 + ((size_t)(g * 512 + uu)) * FEAT;
    float acc = 0.0f;
    for (int j = 0; j < FEAT; ++j) acc += wr[j] * B1[j * HID + k];
    c[g] = acc;
  }
  float4* o = (float4*)(W + ((size_t)(uu * 512 + k)) * 8);
  o[0] = make_float4(c[0], c[1], c[2], c[3]);
  o[1] = make_float4(whh0[((size_t)uu) * 512 + k],
                     whh0[((size_t)(512 + uu)) * 512 + k],
                     whh0[((size_t)(1024 + uu)) * 512 + k],
                     whh0[((size_t)(1536 + uu)) * 512 + k]);
}
// Wf8[(u*512+k)*8 + g] = wih1(g,u,k);  +4+g = whh1(g,u,k)
__global__ void k_wf8(const float* __restrict__ wih1,
                      const float* __restrict__ whh1, float* __restrict__ W) {
  const int idx = blockIdx.x * 256 + threadIdx.x;
  const int uu = idx >> 9, k = idx & 511;
  float4* o = (float4*)(W + ((size_t)(uu * 512 + k)) * 8);
  o[0] = make_float4(wih1[((size_t)uu) * 512 + k],
                     wih1[((size_t)(512 + uu)) * 512 + k],
                     wih1[((size_t)(1024 + uu)) * 512 + k],
                     wih1[((size_t)(1536 + uu)) * 512 + k]);
  o[1] = make_float4(whh1[((size_t)uu) * 512 + k],
                     whh1[((size_t)(512 + uu)) * 512 + k],
                     whh1[((size_t)(1024 + uu)) * 512 + k],
                     whh1[((size_t)(1536 + uu)) * 512 + k]);
}
// wih04[(u*128+k)*4 + g] = wih0(g,u,k)
__global__ void k_wih04(const float* __restrict__ wih0, float* __restrict__ W) {
  const int idx = blockIdx.x * 256 + threadIdx.x;  // u(512) x k(128)
  const int uu = idx >> 7, k = idx & 127;
  float4* o = (float4*)(W + ((size_t)idx) * 4);
  o[0] = make_float4(wih0[((size_t)uu) * FEAT + k],
                     wih0[((size_t)(512 + uu)) * FEAT + k],
                     wih0[((size_t)(1024 + uu)) * FEAT + k],
                     wih0[((size_t)(1536 + uu)) * FEAT + k]);
}
// enc2[(f2*128+k)*2 + j] = enc_w[(f2*2+j)][k]
__global__ void k_enc2(const float* __restrict__ enc_w, float* __restrict__ W) {
  const int idx = blockIdx.x * 256 + threadIdx.x;  // f2(64) x k(128)
  const int f2 = idx >> 7, k = idx & 127;
  W[(size_t)idx * 2 + 0] = enc_w[((size_t)(f2 * 2 + 0)) * FEAT + k];
  W[(size_t)idx * 2 + 1] = enc_w[((size_t)(f2 * 2 + 1)) * FEAT + k];
}
// dec4[(jq*512+k)*4 + jj] = dec_w[(jq*4+jj)][k]
__global__ void k_dec4(const float* __restrict__ dec_w, float* __restrict__ W) {
  const int idx = blockIdx.x * 256 + threadIdx.x;  // jq(32) x k(512)
  const int jq = idx >> 9, k = idx & 511;
  float4* o = (float4*)(W + ((size_t)idx) * 4);
  o[0] = make_float4(dec_w[((size_t)(jq * 4 + 0)) * HID + k],
                     dec_w[((size_t)(jq * 4 + 1)) * HID + k],
                     dec_w[((size_t)(jq * 4 + 2)) * HID + k],
                     dec_w[((size_t)(jq * 4 + 3)) * HID + k]);
}

// ===== ws layout (floats) ==================================================
#define WS_H0A 0
#define WS_H0B 65536
#define WS_H1A 131072
#define WS_H1B 196608
#define WS_BAR 262144
#define WS_B1 263168
#define WS_TE 328704
#define WS_BCOMP 328832
#define WS_WIH04 330880
#define WS_ENC2 593024
#define WS_DEC4 609408
#define WS_WA8 674944
#define WS_WF8 2772096

extern "C" void kernel_launch(void* const* d_in, const int* in_sizes, int n_in,
                              void* d_out, int out_size, void* d_ws,
                              size_t ws_size, hipStream_t stream) {
  const float* x     = (const float*)d_in[0];
  const float* enc_w = (const float*)d_in[1];
  const float* enc_b = (const float*)d_in[2];
  const float* dec_w = (const float*)d_in[3];
  const float* dec_b = (const float*)d_in[4];
  const float* wih0  = (const float*)d_in[5];
  const float* whh0  = (const float*)d_in[6];
  const float* bih0  = (const float*)d_in[7];
  const float* bhh0  = (const float*)d_in[8];
  const float* wih1  = (const float*)d_in[9];
  const float* whh1  = (const float*)d_in[10];
  const float* bih1  = (const float*)d_in[11];
  const float* bhh1  = (const float*)d_in[12];
  float* out = (float*)d_out;

  float* ws = (float*)d_ws;
  float* h0A = ws + WS_H0A;
  float* h0B = ws + WS_H0B;
  float* h1A = ws + WS_H1A;
  float* h1B = ws + WS_H1B;
  int* bar = (int*)(ws + WS_BAR);
  float* B1 = ws + WS_B1;
  float* te = ws + WS_TE;
  float* bcomp = ws + WS_BCOMP;
  float* wih04 = ws + WS_WIH04;
  float* enc2 = ws + WS_ENC2;
  float* dec4 = ws + WS_DEC4;
  float* Wa8 = ws + WS_WA8;
  float* Wf8 = ws + WS_WF8;

  hipMemsetAsync(ws, 0, (size_t)WS_B1 * sizeof(float), stream);

  k_b1<<<256, 256, 0, stream>>>(enc_w, dec_w, B1);
  k_te<<<1, 128, 0, stream>>>(enc_w, enc_b, dec_b, te);
  k_bcomp<<<8, 256, 0, stream>>>(wih0, te, bcomp);
  k_wa8<<<1024, 256, 0, stream>>>(wih0, B1, whh0, Wa8);
  k_wf8<<<1024, 256, 0, stream>>>(wih1, whh1, Wf8);
  k_wih04<<<256, 256, 0, stream>>>(wih0, wih04);
  k_enc2<<<32, 256, 0, stream>>>(enc_w, enc2);
  k_dec4<<<64, 256, 0, stream>>>(dec_w, dec4);

  k_persist<<<NWG, 1024, 0, stream>>>(
      x, enc2, enc_b, wih04, Wa8, Wf8, bih0, bhh0, bih1, bhh1,
      dec4, dec_b, bcomp, h0A, h0B, h1A, h1B, bar, out);
}

// Round 7
// 40342.072 us; speedup vs baseline: 1.0357x; 1.0357x over previous
//
#include <hip/hip_runtime.h>
#include <math.h>

#define HID 512
#define FEAT 128
#define SEQL 512
#define PREDL 128
#define NWG 256
#define HK 516   // LDS row stride (floats) for h tiles
#define EK 132   // LDS row stride for x/e tiles

typedef float v2f __attribute__((ext_vector_type(2)));

__device__ __forceinline__ float sigf_(float x) { return 1.0f / (1.0f + __expf(-x)); }
__device__ __forceinline__ float tanh_(float x) {
  float ax = fabsf(x);
  float e2 = __expf(-2.0f * ax);
  return copysignf((1.0f - e2) / (1.0f + e2), x);
}
__device__ __forceinline__ v2f mkv2(float a, float b) { v2f r; r[0] = a; r[1] = b; return r; }

__device__ __forceinline__ void stg_sc(float* p, float v) {
  __hip_atomic_store(p, v, __ATOMIC_RELAXED, __HIP_MEMORY_SCOPE_AGENT);
}

// ---------------------------------------------------------------------------
// 2-level barrier per bt-group (32 WGs): 8 sub-counters (4 arrivals each,
// sub = wg&7) -> root (8) -> 8 replicated release flags (4 pollers each).
// Relaxed agent atomics only (no cache invalidation) — verified rounds 3-5.
// bar layout (ints): SUB (g*8+s)*32 ; ROOT 2048+g*32 ; FLAG 2304+(g*8+r)*32
// ---------------------------------------------------------------------------
__device__ __forceinline__ void bar_arrive(int* __restrict__ bar, int grp,
                                           int phase, int sub, int tid,
                                           bool& last) {
  __syncthreads();
  if (tid == 0) {
    last = false;
    const int a = __hip_atomic_fetch_add(bar + (grp * 8 + sub) * 32, 1,
                                         __ATOMIC_RELAXED, __HIP_MEMORY_SCOPE_AGENT);
    if (a == 4 * phase - 1) {
      const int rr = __hip_atomic_fetch_add(bar + 2048 + grp * 32, 1,
                                            __ATOMIC_RELAXED, __HIP_MEMORY_SCOPE_AGENT);
      if (rr == 8 * phase - 1) {
#pragma unroll
        for (int r = 0; r < 8; ++r)
          __hip_atomic_store(bar + 2304 + (grp * 8 + r) * 32, phase,
                             __ATOMIC_RELAXED, __HIP_MEMORY_SCOPE_AGENT);
        last = true;
      }
    }
  }
  asm volatile("" ::: "memory");
}
__device__ __forceinline__ void bar_wait(int* __restrict__ bar, int grp,
                                         int phase, int rep, int tid,
                                         bool last) {
  asm volatile("" ::: "memory");
  if (tid == 0 && !last) {
    while (__hip_atomic_load(bar + 2304 + (grp * 8 + rep) * 32,
                             __ATOMIC_RELAXED, __HIP_MEMORY_SCOPE_AGENT) < phase)
      __builtin_amdgcn_s_sleep(1);
  }
  __syncthreads();
}

// ---- LDS scatter of one dense float4 (h block [512k][16b]) ----------------
__device__ __forceinline__ void scat(float* __restrict__ dst, int idx, float4 v) {
  const int k = idx >> 2, bq = (idx & 3) * 4;
  dst[(bq + 0) * HK + k] = v.x;
  dst[(bq + 1) * HK + k] = v.y;
  dst[(bq + 2) * HK + k] = v.z;
  dst[(bq + 3) * HK + k] = v.w;
}

// dense h-block stage: blk = hX + bt*8192, coherent coalesced dwordx4 reads
// (loads + waitcnt in ONE asm block — the verified round-3/4/5 pattern)
__device__ __forceinline__ void stage_hd(float* __restrict__ dst,
                                         const float* __restrict__ blk,
                                         int lane512) {
  const float4* s4 = (const float4*)blk + lane512;
  float4 r0, r1, r2, r3;
  asm volatile(
      "global_load_dwordx4 %0, %4, off sc0 sc1\n\t"
      "global_load_dwordx4 %1, %5, off sc0 sc1\n\t"
      "global_load_dwordx4 %2, %6, off sc0 sc1\n\t"
      "global_load_dwordx4 %3, %7, off sc0 sc1\n\t"
      "s_waitcnt vmcnt(0)"
      : "=&v"(r0), "=&v"(r1), "=&v"(r2), "=&v"(r3)
      : "v"(s4), "v"(s4 + 512), "v"(s4 + 1024), "v"(s4 + 1536)
      : "memory");
  scat(dst, lane512, r0);
  scat(dst, lane512 + 512, r1);
  scat(dst, lane512 + 1024, r2);
  scat(dst, lane512 + 1536, r3);
}

// x tile: plain cached loads -> LDS [16b][EK]
__device__ __forceinline__ void stage_xx(float* __restrict__ dst,
                                         const float* __restrict__ x, int t,
                                         int b0, int lane512) {
  const int bb = lane512 >> 5;
  const int fq = (lane512 & 31) * 4;
  const float4 v =
      *(const float4*)(x + ((size_t)(b0 + bb) * SEQL + t) * FEAT + fq);
  *(float4*)(dst + bb * EK + fq) = v;
}

// ---- packed-FMA GEMV primitives (round 4/5 verified) ----------------------
__device__ __forceinline__ void pkf(v2f& a01, v2f& a23, float4 w, float h) {
  v2f hh; hh[0] = h; hh[1] = h;
  v2f lo; lo[0] = w.x; lo[1] = w.y;
  v2f hi; hi[0] = w.z; hi[1] = w.w;
  a01 = __builtin_elementwise_fma(lo, hh, a01);
  a23 = __builtin_elementwise_fma(hi, hh, a23);
}
__device__ __forceinline__ void gemv_fused8(v2f& a01, v2f& a23,
                                            const float4* __restrict__ W8,
                                            size_t base,
                                            const float* __restrict__ rA,
                                            const float* __restrict__ rB,
                                            int k4b, int k4e) {
#pragma unroll 2
  for (int k4 = k4b; k4 < k4e; ++k4) {
    const float4 hA = *(const float4*)(rA + k4 * 4);
    const float4 hB = *(const float4*)(rB + k4 * 4);
    const size_t o = base + (size_t)k4 * 8;
    pkf(a01, a23, W8[o + 0], hA.x); pkf(a01, a23, W8[o + 1], hB.x);
    pkf(a01, a23, W8[o + 2], hA.y); pkf(a01, a23, W8[o + 3], hB.y);
    pkf(a01, a23, W8[o + 4], hA.z); pkf(a01, a23, W8[o + 5], hB.z);
    pkf(a01, a23, W8[o + 6], hA.w); pkf(a01, a23, W8[o + 7], hB.w);
  }
}
__device__ __forceinline__ void gemv_p4(v2f& a01, v2f& a23,
                                        const float4* __restrict__ W4,
                                        size_t base,
                                        const float* __restrict__ row,
                                        int k4b, int k4e) {
#pragma unroll 4
  for (int k4 = k4b; k4 < k4e; ++k4) {
    const float4 h = *(const float4*)(row + k4 * 4);
    const size_t o = base + (size_t)k4 * 4;
    pkf(a01, a23, W4[o + 0], h.x);
    pkf(a01, a23, W4[o + 1], h.y);
    pkf(a01, a23, W4[o + 2], h.z);
    pkf(a01, a23, W4[o + 3], h.w);
  }
}

__device__ __forceinline__ void act_store(v2f a01, v2f a23, float& c_reg,
                                          float* __restrict__ blk, int cit) {
  const float ig = sigf_(a01[0]), fg = sigf_(a01[1]);
  const float gg = tanh_(a23[0]), og = sigf_(a23[1]);
  const float cn = fg * c_reg + ig * gg;
  c_reg = cn;
  stg_sc(blk + cit, og * tanh_(cn));
}

// ---------------------------------------------------------------------------
// Teacher kernel: 256 WG x 1024 thr. crew A (tid<512): LSTM0 2-way k-split.
// crew B: LSTM1(t-1) 2-way k-split. Staging and encoder overlap cross-wave
// (no barrier between them).
// ---------------------------------------------------------------------------
__global__ __launch_bounds__(1024, 1) void k_teacher(
    const float* __restrict__ x,
    const float* __restrict__ enc2, const float* __restrict__ enc_b,
    const float* __restrict__ wih04, const float* __restrict__ whh04,
    const float* __restrict__ Wf8,
    const float* __restrict__ bih0, const float* __restrict__ bhh0,
    const float* __restrict__ bih1, const float* __restrict__ bhh1,
    float* __restrict__ h0A, float* __restrict__ h0B,
    float* __restrict__ h1A, float* __restrict__ h1B,
    float* __restrict__ cbuf, int* __restrict__ bar) {
  __shared__ float s_h0[16 * HK];
  __shared__ float s_h1[16 * HK];
  __shared__ float s_x[16 * EK];
  __shared__ float s_e[16 * EK];
  __shared__ float4 s_red4[512];

  const int wg = blockIdx.x;
  const int tid = threadIdx.x;
  const int ut = (wg & 7) * 4 + ((wg >> 3) & 3);  // XCD-affine unit tile
  const int bt = wg >> 5;
  const int b0 = bt * 16;
  const int rep = wg & 7;
  const int o = tid & 255;
  const int u = o >> 4, b = o & 15;
  const int ug = ut * 16 + u;
  const int cit = ug * 16 + b;           // dense block offset
  const int crewB = tid >> 9;
  const int khalf = (tid >> 8) & 1;
  const int lane512 = tid & 511;

  float* h0b[2] = {h0A, h0B};
  float* h1b[2] = {h1A, h1B};
  const float* sh0row = s_h0 + b * HK;
  const float* sh1row = s_h1 + b * HK;
  const float* serow = s_e + b * EK;

  const float4* W4h = (const float4*)whh04;  // dense whh0, base ug*512
  const float4* W4i = (const float4*)wih04;  // base ug*128
  const float4* W8f = (const float4*)Wf8;    // [wih1|whh1], base ug*1024
  const size_t baseH = (size_t)ug * 512;
  const size_t baseI = (size_t)ug * 128;
  const size_t baseF = (size_t)ug * 1024;

  const float bt00 = bih0[ug] + bhh0[ug];
  const float bt01 = bih0[512 + ug] + bhh0[512 + ug];
  const float bt02 = bih0[1024 + ug] + bhh0[1024 + ug];
  const float bt03 = bih0[1536 + ug] + bhh0[1536 + ug];
  const float b10 = bih1[ug] + bhh1[ug];
  const float b11 = bih1[512 + ug] + bhh1[512 + ug];
  const float b12 = bih1[1024 + ug] + bhh1[1024 + ug];
  const float b13 = bih1[1536 + ug] + bhh1[1536 + ug];

  // encoder role (all 1024 threads): 2 f-outputs for one batch
  const int eb = tid & 15;
  const int f2 = tid >> 4;  // 0..63
  const float4* EF4 = (const float4*)enc2 + (size_t)f2 * 64;
  const float encb0 = enc_b[f2 * 2], encb1 = enc_b[f2 * 2 + 1];
  const float* sxrow = s_x + eb * EK;

  float c_reg = 0.0f;
  int ph = 0;
  bool lastf = false;

  if (tid < 512) stage_xx(s_x, x, 0, b0, lane512);
  __syncthreads();

  for (int t = 0; t < SEQL; ++t) {
    // --- stage h (coherent, dense); waves overlap with encoder below ------
    const float* blk = ((tid < 512) ? h0b[(t + 1) & 1] : h1b[t & 1]) + bt * 8192;
    float* dst = (tid < 512) ? s_h0 : s_h1;
    stage_hd(dst, blk, lane512);

    // --- encoder ----------------------------------------------------------
    {
      v2f acc = mkv2(encb0, encb1);
#pragma unroll 8
      for (int k2 = 0; k2 < 64; ++k2) {
        const float4 w = EF4[k2];
        const float hv0 = sxrow[2 * k2], hv1 = sxrow[2 * k2 + 1];
        acc = __builtin_elementwise_fma(mkv2(w.x, w.y), mkv2(hv0, hv0), acc);
        acc = __builtin_elementwise_fma(mkv2(w.z, w.w), mkv2(hv1, hv1), acc);
      }
      s_e[eb * EK + f2 * 2] = acc[0];
      s_e[eb * EK + f2 * 2 + 1] = acc[1];
    }
    __syncthreads();

    // --- cells ------------------------------------------------------------
    v2f a01, a23;
    if (!crewB) {  // LSTM0(t), 2-way k-split
      if (!khalf) {
        a01 = mkv2(bt00, bt01); a23 = mkv2(bt02, bt03);
        gemv_p4(a01, a23, W4h, baseH, sh0row, 0, 80);
      } else {
        a01 = mkv2(0.f, 0.f); a23 = mkv2(0.f, 0.f);
        gemv_p4(a01, a23, W4h, baseH, sh0row, 80, 128);
        gemv_p4(a01, a23, W4i, baseI, serow, 0, 32);
        s_red4[o] = make_float4(a01[0], a01[1], a23[0], a23[1]);
      }
    } else {  // LSTM1(t-1), 2-way k-split
      if (!khalf) {
        a01 = mkv2(b10, b11); a23 = mkv2(b12, b13);
        gemv_fused8(a01, a23, W8f, baseF, sh0row, sh1row, 0, 64);
      } else {
        a01 = mkv2(0.f, 0.f); a23 = mkv2(0.f, 0.f);
        gemv_fused8(a01, a23, W8f, baseF, sh0row, sh1row, 64, 128);
        s_red4[256 + o] = make_float4(a01[0], a01[1], a23[0], a23[1]);
      }
    }
    __syncthreads();
    if (!khalf) {
      const float4 p = s_red4[(crewB ? 256 : 0) + o];
      a01[0] += p.x; a01[1] += p.y; a23[0] += p.z; a23[1] += p.w;
      if (!crewB) act_store(a01, a23, c_reg, h0b[t & 1] + bt * 8192, cit);
      else if (t > 0) act_store(a01, a23, c_reg, h1b[(t + 1) & 1] + bt * 8192, cit);
    }
    bar_arrive(bar, bt, ++ph, rep, tid, lastf);
    if (tid < 512 && t + 1 < SEQL) stage_xx(s_x, x, t + 1, b0, lane512);
    bar_wait(bar, bt, ph, rep, tid, lastf);
  }

  // save cell states for the AR kernel
  if (tid < 256) cbuf[(size_t)wg * 256 + o] = c_reg;
  else if (tid >= 512 && tid < 768) cbuf[65536 + (size_t)wg * 256 + o] = c_reg;
}

// ---------------------------------------------------------------------------
// AR kernel: LSTM1(511) then 127 steps of {LSTM0-AR || decode ; LSTM1 4-way}.
// ---------------------------------------------------------------------------
__global__ __launch_bounds__(1024, 1) void k_ar(
    const float* __restrict__ Wa8, const float* __restrict__ Wf8,
    const float* __restrict__ bih0, const float* __restrict__ bhh0,
    const float* __restrict__ bih1, const float* __restrict__ bhh1,
    const float* __restrict__ dec4, const float* __restrict__ dec_b,
    const float* __restrict__ bcomp,
    float* __restrict__ h0A, float* __restrict__ h0B,
    float* __restrict__ h1A, float* __restrict__ h1B,
    float* __restrict__ cbuf, int* __restrict__ bar,
    float* __restrict__ out) {
  __shared__ float s_h0[16 * HK];
  __shared__ float s_h1[16 * HK];
  __shared__ float4 s_red4[768];

  const int wg = blockIdx.x;
  const int tid = threadIdx.x;
  const int ut = (wg & 7) * 4 + ((wg >> 3) & 3);
  const int bt = wg >> 5;
  const int b0 = bt * 16;
  const int rep = wg & 7;
  const int o = tid & 255;
  const int u = o >> 4, b = o & 15;
  const int ug = ut * 16 + u;
  const int cit = ug * 16 + b;
  const int crewB = tid >> 9;
  const int khalf = (tid >> 8) & 1;
  const int lane512 = tid & 511;
  const int q4 = ((tid >> 8) + 2) & 3;  // owners q4==0 (tid 512..767)

  float* h0b[2] = {h0A, h0B};
  float* h1b[2] = {h1A, h1B};
  const float* sh0row = s_h0 + b * HK;
  const float* sh1row = s_h1 + b * HK;

  const float4* W8a = (const float4*)Wa8;  // [Wcomp|whh0]
  const float4* W8f = (const float4*)Wf8;  // [wih1|whh1]
  const size_t baseG = (size_t)ug * 1024;

  const float ba00 = bih0[ug] + bhh0[ug] + bcomp[ug];
  const float ba01 = bih0[512 + ug] + bhh0[512 + ug] + bcomp[512 + ug];
  const float ba02 = bih0[1024 + ug] + bhh0[1024 + ug] + bcomp[1024 + ug];
  const float ba03 = bih0[1536 + ug] + bhh0[1536 + ug] + bcomp[1536 + ug];
  const float b10 = bih1[ug] + bhh1[ug];
  const float b11 = bih1[512 + ug] + bhh1[512 + ug];
  const float b12 = bih1[1024 + ug] + bhh1[1024 + ug];
  const float b13 = bih1[1536 + ug] + bhh1[1536 + ug];

  // decoder role (crew B): 4 dec rows x 1 batch per thread
  const int cb = tid & 511;
  const int jq = cb >> 4, db = cb & 15;
  const float4* D4 = (const float4*)dec4;
  const size_t baseD = (size_t)jq * 512;
  const float db0 = dec_b[jq * 4], db1 = dec_b[jq * 4 + 1];
  const float db2 = dec_b[jq * 4 + 2], db3 = dec_b[jq * 4 + 3];
  const float* dhrow = s_h1 + db * HK;

  // restore cell state
  float c_reg = 0.0f;
  if (tid < 256) c_reg = cbuf[(size_t)wg * 256 + o];
  else if (tid >= 512 && tid < 768) c_reg = cbuf[65536 + (size_t)wg * 256 + o];

  int ph = 0;
  bool lastf = false;

  // ---- LSTM1(511): A = h0(511)=h0b[1], Hin = h1(510)=h1b[0], 4-way -------
  if (tid < 512) stage_hd(s_h0, h0b[1] + bt * 8192, lane512);
  else stage_hd(s_h1, h1b[0] + bt * 8192, lane512);
  __syncthreads();
  {
    v2f a01, a23;
    if (q4 == 0) { a01 = mkv2(b10, b11); a23 = mkv2(b12, b13); }
    else { a01 = mkv2(0.f, 0.f); a23 = mkv2(0.f, 0.f); }
    gemv_fused8(a01, a23, W8f, baseG, sh0row, sh1row, q4 * 32, q4 * 32 + 32);
    if (q4) s_red4[(q4 - 1) * 256 + o] = make_float4(a01[0], a01[1], a23[0], a23[1]);
    __syncthreads();
    if (q4 == 0) {
      const float4 p0 = s_red4[o], p1 = s_red4[256 + o], p2 = s_red4[512 + o];
      a01[0] += p0.x + p1.x + p2.x; a01[1] += p0.y + p1.y + p2.y;
      a23[0] += p0.z + p1.z + p2.z; a23[1] += p0.w + p1.w + p2.w;
      act_store(a01, a23, c_reg, h1b[1] + bt * 8192, cit);
    }
  }
  bar_arrive(bar, bt, ++ph, rep, tid, lastf);
  bar_wait(bar, bt, ph, rep, tid, lastf);

  // ---- autoregressive loop ------------------------------------------------
  for (int t = SEQL; t < SEQL + PREDL - 1; ++t) {
    // phase 1: crew A LSTM0-AR(t) 2-way; crew B decode h1(t-1)
    if (tid < 512) stage_hd(s_h1, h1b[(t + 1) & 1] + bt * 8192, lane512);
    else stage_hd(s_h0, h0b[(t + 1) & 1] + bt * 8192, lane512);
    __syncthreads();
    v2f a01, a23;
    if (!crewB) {
      if (!khalf) { a01 = mkv2(ba00, ba01); a23 = mkv2(ba02, ba03); }
      else { a01 = mkv2(0.f, 0.f); a23 = mkv2(0.f, 0.f); }
      gemv_fused8(a01, a23, W8a, baseG, sh1row, sh0row,
                  khalf ? 64 : 0, khalf ? 128 : 64);
      if (khalf) s_red4[o] = make_float4(a01[0], a01[1], a23[0], a23[1]);
    } else {
      v2f d01 = mkv2(db0, db1), d23 = mkv2(db2, db3);
      gemv_p4(d01, d23, D4, baseD, dhrow, 0, 128);
      *(float4*)(out + ((size_t)(b0 + db) * PREDL + (t - SEQL)) * FEAT + jq * 4) =
          make_float4(d01[0], d01[1], d23[0], d23[1]);
    }
    __syncthreads();
    if (!crewB && !khalf) {
      const float4 p = s_red4[o];
      a01[0] += p.x; a01[1] += p.y; a23[0] += p.z; a23[1] += p.w;
      act_store(a01, a23, c_reg, h0b[t & 1] + bt * 8192, cit);
    }
    bar_arrive(bar, bt, ++ph, rep, tid, lastf);
    bar_wait(bar, bt, ph, rep, tid, lastf);

    // phase 2: LSTM1(t) 4-way; Hin = h1(t-1) still in s_h1
    if (tid < 512) stage_hd(s_h0, h0b[t & 1] + bt * 8192, lane512);
    __syncthreads();
    {
      v2f c01, c23;
      if (q4 == 0) { c01 = mkv2(b10, b11); c23 = mkv2(b12, b13); }
      else { c01 = mkv2(0.f, 0.f); c23 = mkv2(0.f, 0.f); }
      gemv_fused8(c01, c23, W8f, baseG, sh0row, sh1row, q4 * 32, q4 * 32 + 32);
      if (q4) s_red4[(q4 - 1) * 256 + o] = make_float4(c01[0], c01[1], c23[0], c23[1]);
      __syncthreads();
      if (q4 == 0) {
        const float4 p0 = s_red4[o], p1 = s_red4[256 + o], p2 = s_red4[512 + o];
        c01[0] += p0.x + p1.x + p2.x; c01[1] += p0.y + p1.y + p2.y;
        c23[0] += p0.z + p1.z + p2.z; c23[1] += p0.w + p1.w + p2.w;
        act_store(c01, c23, c_reg, h1b[t & 1] + bt * 8192, cit);
      }
    }
    bar_arrive(bar, bt, ++ph, rep, tid, lastf);
    bar_wait(bar, bt, ph, rep, tid, lastf);
  }

  // final decode: h1(638) = h1b[0], step 127
  if (tid < 512) stage_hd(s_h1, h1b[0] + bt * 8192, lane512);
  __syncthreads();
  if (crewB) {
    v2f d01 = mkv2(db0, db1), d23 = mkv2(db2, db3);
    gemv_p4(d01, d23, D4, baseD, dhrow, 0, 128);
    *(float4*)(out + ((size_t)(b0 + db) * PREDL + (PREDL - 1)) * FEAT + jq * 4) =
        make_float4(d01[0], d01[1], d23[0], d23[1]);
  }
}

// ===== prologue ============================================================
__global__ void k_b1(const float* __restrict__ enc_w,
                     const float* __restrict__ dec_w, float* __restrict__ B1) {
  const int idx = blockIdx.x * 256 + threadIdx.x;
  const int j = idx >> 9, m = idx & 511;
  float acc = 0.0f;
  for (int k = 0; k < FEAT; ++k) acc += enc_w[j * FEAT + k] * dec_w[k * HID + m];
  B1[idx] = acc;
}
__global__ void k_te(const float* __restrict__ enc_w,
                     const float* __restrict__ enc_b,
                     const float* __restrict__ dec_b, float* __restrict__ te) {
  const int j = threadIdx.x;
  float acc = enc_b[j];
  for (int k = 0; k < FEAT; ++k) acc += dec_b[k] * enc_w[j * FEAT + k];
  te[j] = acc;
}
__global__ void k_bcomp(const float* __restrict__ wih0,
                        const float* __restrict__ te, float* __restrict__ bc) {
  const int n = blockIdx.x * 256 + threadIdx.x;
  float acc = 0.0f;
  for (int j = 0; j < FEAT; ++j) acc += wih0[n * FEAT + j] * te[j];
  bc[n] = acc;
}
__global__ void k_wa8(const float* __restrict__ wih0,
                      const float* __restrict__ B1,
                      const float* __restrict__ whh0, float* __restrict__ W) {
  const int idx = blockIdx.x * 256 + threadIdx.x;
  const int uu = idx >> 9, k = idx & 511;
  float c[4];
#pragma unroll
  for (int g = 0; g < 4; ++g) {
    const float* wr = wih0 + ((size_t)(g * 512 + uu)) * FEAT;
    float acc = 0.0f;
    for (int j = 0; j < FEAT; ++j) acc += wr[j] * B1[j * HID + k];
    c[g] = acc;
  }
  float4* op = (float4*)(W + ((size_t)(uu * 512 + k)) * 8);
  op[0] = make_float4(c[0], c[1], c[2], c[3]);
  op[1] = make_float4(whh0[((size_t)uu) * 512 + k],
                      whh0[((size_t)(512 + uu)) * 512 + k],
                      whh0[((size_t)(1024 + uu)) * 512 + k],
                      whh0[((size_t)(1536 + uu)) * 512 + k]);
}
__global__ void k_wf8(const float* __restrict__ wih1,
                      const float* __restrict__ whh1, float* __restrict__ W) {
  const int idx = blockIdx.x * 256 + threadIdx.x;
  const int uu = idx >> 9, k = idx & 511;
  float4* op = (float4*)(W + ((size_t)(uu * 512 + k)) * 8);
  op[0] = make_float4(wih1[((size_t)uu) * 512 + k],
                      wih1[((size_t)(512 + uu)) * 512 + k],
                      wih1[((size_t)(1024 + uu)) * 512 + k],
                      wih1[((size_t)(1536 + uu)) * 512 + k]);
  op[1] = make_float4(whh1[((size_t)uu) * 512 + k],
                      whh1[((size_t)(512 + uu)) * 512 + k],
                      whh1[((size_t)(1024 + uu)) * 512 + k],
                      whh1[((size_t)(1536 + uu)) * 512 + k]);
}
__global__ void k_wih04(const float* __restrict__ wih0, float* __restrict__ W) {
  const int idx = blockIdx.x * 256 + threadIdx.x;  // u(512) x k(128)
  const int uu = idx >> 7, k = idx & 127;
  float4* op = (float4*)(W + ((size_t)idx) * 4);
  op[0] = make_float4(wih0[((size_t)uu) * FEAT + k],
                      wih0[((size_t)(512 + uu)) * FEAT + k],
                      wih0[((size_t)(1024 + uu)) * FEAT + k],
                      wih0[((size_t)(1536 + uu)) * FEAT + k]);
}
// dense whh0 4-interleave: W[(u*512+k)*4+g] = whh0[g*512+u][k]
__global__ void k_whh04(const float* __restrict__ whh0, float* __restrict__ W) {
  const int idx = blockIdx.x * 256 + threadIdx.x;  // u(512) x k(512)
  const int uu = idx >> 9, k = idx & 511;
  float4* op = (float4*)(W + ((size_t)idx) * 4);
  op[0] = make_float4(whh0[((size_t)uu) * 512 + k],
                      whh0[((size_t)(512 + uu)) * 512 + k],
                      whh0[((size_t)(1024 + uu)) * 512 + k],
                      whh0[((size_t)(1536 + uu)) * 512 + k]);
}
__global__ void k_enc2(const float* __restrict__ enc_w, float* __restrict__ W) {
  const int idx = blockIdx.x * 256 + threadIdx.x;  // f2(64) x k(128)
  const int f2 = idx >> 7, k = idx & 127;
  W[(size_t)idx * 2 + 0] = enc_w[((size_t)(f2 * 2 + 0)) * FEAT + k];
  W[(size_t)idx * 2 + 1] = enc_w[((size_t)(f2 * 2 + 1)) * FEAT + k];
}
__global__ void k_dec4(const float* __restrict__ dec_w, float* __restrict__ W) {
  const int idx = blockIdx.x * 256 + threadIdx.x;  // jq(32) x k(512)
  const int jq = idx >> 9, k = idx & 511;
  float4* op = (float4*)(W + ((size_t)idx) * 4);
  op[0] = make_float4(dec_w[((size_t)(jq * 4 + 0)) * HID + k],
                      dec_w[((size_t)(jq * 4 + 1)) * HID + k],
                      dec_w[((size_t)(jq * 4 + 2)) * HID + k],
                      dec_w[((size_t)(jq * 4 + 3)) * HID + k]);
}

// ===== ws layout (floats) ==================================================
#define WS_H0A 0
#define WS_H0B 65536
#define WS_H1A 131072
#define WS_H1B 196608
#define WS_CBUF 262144
#define WS_BART 393216
#define WS_BARA 401408
#define WS_B1 409600
#define WS_TE 475136
#define WS_BCOMP 475264
#define WS_WIH04 477312
#define WS_WHH04 739456
#define WS_ENC2 1788032
#define WS_DEC4 1804416
#define WS_WA8 2066560
#define WS_WF8 4163712

extern "C" void kernel_launch(void* const* d_in, const int* in_sizes, int n_in,
                              void* d_out, int out_size, void* d_ws,
                              size_t ws_size, hipStream_t stream) {
  const float* x     = (const float*)d_in[0];
  const float* enc_w = (const float*)d_in[1];
  const float* enc_b = (const float*)d_in[2];
  const float* dec_w = (const float*)d_in[3];
  const float* dec_b = (const float*)d_in[4];
  const float* wih0  = (const float*)d_in[5];
  const float* whh0  = (const float*)d_in[6];
  const float* bih0  = (const float*)d_in[7];
  const float* bhh0  = (const float*)d_in[8];
  const float* wih1  = (const float*)d_in[9];
  const float* whh1  = (const float*)d_in[10];
  const float* bih1  = (const float*)d_in[11];
  const float* bhh1  = (const float*)d_in[12];
  float* out = (float*)d_out;

  float* ws = (float*)d_ws;
  float* h0A = ws + WS_H0A;
  float* h0B = ws + WS_H0B;
  float* h1A = ws + WS_H1A;
  float* h1B = ws + WS_H1B;
  float* cbuf = ws + WS_CBUF;
  int* barT = (int*)(ws + WS_BART);
  int* barA = (int*)(ws + WS_BARA);
  float* B1 = ws + WS_B1;
  float* te = ws + WS_TE;
  float* bcomp = ws + WS_BCOMP;
  float* wih04 = ws + WS_WIH04;
  float* whh04 = ws + WS_WHH04;
  float* enc2 = ws + WS_ENC2;
  float* dec4 = ws + WS_DEC4;
  float* Wa8 = ws + WS_WA8;
  float* Wf8 = ws + WS_WF8;

  // zero h states + both barrier arrays each launch
  (void)hipMemsetAsync(ws, 0, (size_t)262144 * sizeof(float), stream);
  (void)hipMemsetAsync(ws + WS_BART, 0, (size_t)16384 * sizeof(float), stream);

  k_b1<<<256, 256, 0, stream>>>(enc_w, dec_w, B1);
  k_te<<<1, 128, 0, stream>>>(enc_w, enc_b, dec_b, te);
  k_bcomp<<<8, 256, 0, stream>>>(wih0, te, bcomp);
  k_wa8<<<1024, 256, 0, stream>>>(wih0, B1, whh0, Wa8);
  k_wf8<<<1024, 256, 0, stream>>>(wih1, whh1, Wf8);
  k_wih04<<<256, 256, 0, stream>>>(wih0, wih04);
  k_whh04<<<1024, 256, 0, stream>>>(whh0, whh04);
  k_enc2<<<32, 256, 0, stream>>>(enc_w, enc2);
  k_dec4<<<64, 256, 0, stream>>>(dec_w, dec4);

  k_teacher<<<NWG, 1024, 0, stream>>>(
      x, enc2, enc_b, wih04, whh04, Wf8, bih0, bhh0, bih1, bhh1,
      h0A, h0B, h1A, h1B, cbuf, barT);

  k_ar<<<NWG, 1024, 0, stream>>>(
      Wa8, Wf8, bih0, bhh0, bih1, bhh1, dec4, dec_b, bcomp,
      h0A, h0B, h1A, h1B, cbuf, barA, out);
}